// Round 1
// 358.195 us; speedup vs baseline: 1.0306x; 1.0306x over previous
//
#include <hip/hip_runtime.h>
#include <math.h>

using short8  = __attribute__((ext_vector_type(8))) short;
using floatx4 = __attribute__((ext_vector_type(4))) float;

namespace {
constexpr int   kB      = 256;
constexpr int   kD      = 128;
constexpr int   kC      = 100000;
constexpr float kScale  = 35.0f;
constexpr float kCosM   = 0.87758256189037276f;   // cos(0.5)
constexpr float kSinM   = 0.47942553860420301f;   // sin(0.5)
constexpr float kThresh = -0.87758256189037276f;  // -cos(0.5)
constexpr float kExt    = -0.5f * 0.47942553860420301f; // -m*sin(m)

// ws layout: feat bf16 (256 rows x 256B) then rf (256 f32). Weights never staged.
constexpr size_t kFeatBfOff = 0;
constexpr size_t kRfOff     = (size_t)kB * 256;
}

__device__ inline unsigned short f2bf(float f) {
    unsigned u = __builtin_bit_cast(unsigned, f);
    return (unsigned short)((u + 0x7fffu + ((u >> 16) & 1u)) >> 16);  // RNE
}

__device__ inline void async16(void* lds, const void* g) {
    __builtin_amdgcn_global_load_lds(
        (const __attribute__((address_space(1))) void*)g,
        (__attribute__((address_space(3))) void*)lds, 16, 0, 0);
}

// ---------------- feat-only prep: 64 blocks, one wave per row (256 rows)
__global__ __launch_bounds__(256)
void arcface_prep(const float* __restrict__ feat, unsigned char* __restrict__ ws) {
    const int wid = blockIdx.x * 4 + (threadIdx.x >> 6);
    const int l   = threadIdx.x & 63;
    const float2 v = *(const float2*)(feat + (size_t)wid * kD + 2 * l);
    float s = v.x * v.x + v.y * v.y;
    #pragma unroll
    for (int off = 32; off > 0; off >>= 1) s += __shfl_down(s, off, 64);
    const unsigned packed = (unsigned)f2bf(v.x) | ((unsigned)f2bf(v.y) << 16);
    ((unsigned*)(ws + kFeatBfOff + (size_t)wid * 256))[l] = packed;
    if (l == 0) *(float*)(ws + kRfOff + (size_t)wid * 4) = rsqrtf(s);
}

// ---------------- fused GEMM: stages f32 weights directly, norms computed in-kernel.
// One N=64 tile per block, M=256. Source-swizzled staging (linear LDS dest,
// XOR'd global source; involution re-applied on the LDS reads).
__global__ __launch_bounds__(256, 2)
void arcface_gemm(const float* __restrict__ wgt,
                  const unsigned char* __restrict__ ws,
                  float* __restrict__ out_cos,
                  float* __restrict__ out_marg,
                  float* __restrict__ out_ip) {
    __shared__ float sW[64 * 128];           // 32 KB f32 weight tile (swizzled)
    __shared__ float sScr[4][16 * 68];       // per-wave transpose scratch
    __shared__ float sRw[64];                // per-tile weight-row rsqrt norms

    const int t   = threadIdx.x;
    const int l   = t & 63;
    const int w   = t >> 6;
    const int q   = l >> 4;
    const int c16 = l & 15;
    const int m0  = w * 64;
    const int c0  = blockIdx.x * 64;

    // stage 32 KB: 8 passes x 256 thr x 16B. LDS dest linear; source XOR-swizzled
    // at 16B granularity: swz(row) = ((row&15)<<5) | ((row&4)<<2). Last tile's
    // out-of-range rows clamp to row kC-1 (outputs there are masked anyway).
    #pragma unroll
    for (int p = 0; p < 8; ++p) {
        const int o    = p * 4096 + t * 16;
        const int row  = o >> 9;
        const int col  = o & 511;
        const int swz  = ((row & 15) << 5) | ((row & 4) << 2);
        const int srow = min(c0 + row, kC - 1);
        async16((char*)sW + o, (const char*)wgt + (size_t)srow * 512 + (col ^ swz));
    }

    const short* featbf = (const short*)(ws + kFeatBfOff);
    const float* rf_g   = (const float*)(ws + kRfOff);

    // A fragments: wave's 64 m-rows x K=128 (m = lane&15, k = quad*8 + j)
    short8 aF[4][4];
    #pragma unroll
    for (int mi = 0; mi < 4; ++mi)
        #pragma unroll
        for (int kq = 0; kq < 4; ++kq)
            aF[mi][kq] = *(const short8*)(featbf + (size_t)(m0 + mi * 16 + c16) * kD + kq * 32 + q * 8);

    __syncthreads();   // drains vmcnt(0): W tile + aF ready

    floatx4 acc[4][4];
    #pragma unroll
    for (int mi = 0; mi < 4; ++mi)
        #pragma unroll
        for (int nt = 0; nt < 4; ++nt)
            acc[mi][nt] = (floatx4){0.f, 0.f, 0.f, 0.f};

    float s2[4] = {0.f, 0.f, 0.f, 0.f};     // per-lane partial |w|^2 for rows nt*16+c16

    #pragma unroll
    for (int kq = 0; kq < 4; ++kq) {
        short8 bF[4];
        #pragma unroll
        for (int nt = 0; nt < 4; ++nt) {
            const int row = nt * 16 + c16;
            const int swz = ((row & 15) << 5) | ((row & 4) << 2);
            const int cb  = kq * 128 + q * 32;                   // fragment k-bytes (f32)
            const floatx4 w0 = *(const floatx4*)((const char*)sW + row * 512 + ((cb)      ^ swz));
            const floatx4 w1 = *(const floatx4*)((const char*)sW + row * 512 + ((cb + 16) ^ swz));
            s2[nt] += w0[0]*w0[0] + w0[1]*w0[1] + w0[2]*w0[2] + w0[3]*w0[3]
                    + w1[0]*w1[0] + w1[1]*w1[1] + w1[2]*w1[2] + w1[3]*w1[3];
            short8 b;
            b[0] = (short)f2bf(w0[0]); b[1] = (short)f2bf(w0[1]);
            b[2] = (short)f2bf(w0[2]); b[3] = (short)f2bf(w0[3]);
            b[4] = (short)f2bf(w1[0]); b[5] = (short)f2bf(w1[1]);
            b[6] = (short)f2bf(w1[2]); b[7] = (short)f2bf(w1[3]);
            bF[nt] = b;
        }
        #pragma unroll
        for (int mi = 0; mi < 4; ++mi)
            #pragma unroll
            for (int nt = 0; nt < 4; ++nt)
                acc[mi][nt] = __builtin_amdgcn_mfma_f32_16x16x32_bf16(
                    aF[mi][kq], bF[nt], acc[mi][nt], 0, 0, 0);
    }

    // row norms: each lane holds 32/128 of rows nt*16+c16; reduce across the 4
    // q-lanes sharing c16 (xor 16, 32). All 4 waves write identical values — benign.
    #pragma unroll
    for (int nt = 0; nt < 4; ++nt) {
        float s = s2[nt];
        s += __shfl_xor(s, 16, 64);
        s += __shfl_xor(s, 32, 64);
        sRw[nt * 16 + c16] = rsqrtf(s);
    }

    // epilogue: per-wave LDS transpose -> coalesced nontemporal float4 stores
    float* scr = &sScr[w][0];
    const int  c   = c0 + c16 * 4;
    const bool cok = c < kC;                       // kC % 4 == 0, so whole quad in/out
    const floatx4 rw4 = *(const floatx4*)(sRw + c16 * 4);   // own-wave writes, lgkm-ordered

    #pragma unroll
    for (int mi = 0; mi < 4; ++mi) {
        #pragma unroll
        for (int nt = 0; nt < 4; ++nt)
            #pragma unroll
            for (int r = 0; r < 4; ++r)
                scr[(q * 4 + r) * 68 + nt * 16 + c16] = acc[mi][nt][r];
        #pragma unroll
        for (int jj = 0; jj < 4; ++jj) {
            const int rr = q + 4 * jj;
            const floatx4 ip = *(const floatx4*)(scr + rr * 68 + c16 * 4);
            const int m = m0 + mi * 16 + rr;
            if (cok) {
                const float rf = rf_g[m];
                const floatx4 cs = ip * rf * rw4;
                const size_t o = (size_t)m * kC + c;
                __builtin_nontemporal_store(ip,           (floatx4*)(out_ip + o));
                __builtin_nontemporal_store(cs,           (floatx4*)(out_cos + o));
                __builtin_nontemporal_store(cs * kScale,  (floatx4*)(out_marg + o));
            }
        }
    }
}

// ---------------- gt-column fixup on marginal logits
__global__ void arcface_fixup(const int* __restrict__ label,
                              const float* __restrict__ out_cos,
                              float* __restrict__ out_marg) {
    const int b = threadIdx.x;
    bool is64 = true;
    #pragma unroll
    for (int i = 1; i < 24; i += 2) is64 = is64 && (label[i] == 0);
    const int c = is64 ? label[2 * b] : label[b];
    const size_t idx = (size_t)b * kC + c;
    const float cosv = out_cos[idx];
    const float cc = fminf(1.f, fmaxf(-1.f, cosv));
    float marg;
    if (cosv > kThresh) {
        marg = cc * kCosM - sqrtf(fmaxf(0.f, 1.f - cc * cc)) * kSinM;
    } else {
        marg = cc + kExt;
    }
    out_marg[idx] = kScale * marg;
}

extern "C" void kernel_launch(void* const* d_in, const int* in_sizes, int n_in,
                              void* d_out, int out_size, void* d_ws, size_t ws_size,
                              hipStream_t stream) {
    const float* feat  = (const float*)d_in[0];
    const float* wgt   = (const float*)d_in[1];
    const int*   label = (const int*)d_in[2];
    float* out_cos  = (float*)d_out;
    float* out_marg = out_cos  + (size_t)kB * kC;
    float* out_ip   = out_marg + (size_t)kB * kC;
    unsigned char* ws = (unsigned char*)d_ws;

    arcface_prep<<<64, 256, 0, stream>>>(feat, ws);
    arcface_gemm<<<(kC + 63) / 64, 256, 0, stream>>>(wgt, ws, out_cos, out_marg, out_ip);
    arcface_fixup<<<1, 256, 0, stream>>>(label, out_cos, out_marg);
}